// Round 10
// baseline (30.421 us; speedup 1.0000x reference)
//
#include <hip/hip_runtime.h>
#include <stdint.h>

#define H 512
#define W 512
#define HW (H * W)
#define KT 81     // 9x9 taps per pixel
#define PAD 4
#define SEGW 64   // pixels per block (one row segment)

// clang vector type (NOT HIP_vector_type struct) — accepted by
// __builtin_nontemporal_load/store.
typedef float f4 __attribute__((ext_vector_type(4)));

__device__ __forceinline__ int reflect_idx(int p) {
    // jnp.pad mode="reflect": pad (4) < 512, one fold suffices
    if (p < 0) p = -p;
    if (p >= H) p = 2 * H - 2 - p;
    return p;
}

// R4 structure (best so far, 24.2us): 192 threads = 3 waves; wave c computes
// channel c of a 64-pixel row segment. Weights staged coalesced -> LDS, read
// back per-lane at dword stride 81 (bank = (17*l+t) mod 32 = permutation ->
// conflict-free, pairs into ds_read2_b32).
// NEW: kf staging uses NON-TEMPORAL loads and out uses non-temporal stores.
// kf is an 85MB zero-reuse stream that otherwise flushes the 4MB per-XCD L2
// ~3x per dispatch, evicting the x band (3MB, 9x reuse) -> x reads miss to
// L3/HBM. NT-streaming kf should leave x L2-resident.
__global__ __launch_bounds__(192) void svblur_kernel(
    const float* __restrict__ x,
    const float* __restrict__ kf,
    float* __restrict__ out)
{
    __shared__ float wlds[SEGW * KT];   // 20736 B

    const int tid = (int)threadIdx.x;
    const int l   = tid & 63;           // lane = pixel in segment
    const int wv  = tid >> 6;           // wave id = channel (0..2)
    const int bid = (int)blockIdx.x;
    const int h   = bid >> 3;           // 512 rows
    const int w0  = (bid & 7) << 6;     // 8 segments of 64 px per row

    // ---- Stage weights: 5184 contiguous dwords = 1296 float4, 7 ops/wave,
    // non-temporal (zero reuse; don't let them occupy L2).
    {
        const f4* ws = (const f4*)(kf + ((size_t)h * W + w0) * KT);
        f4* wd = (f4*)wlds;
#pragma unroll
        for (int it = 0; it < 7; ++it) {
            int idx = (wv * 7 + it) * 64 + l;
            if (idx < (SEGW * KT) / 4)
                wd[idx] = __builtin_nontemporal_load(&ws[idx]);
        }
    }
    __syncthreads();

    // Reflected column offsets, computed once; x loads are then
    // global_load_dword v, voff, s[rowbase] (row base is wave-uniform SGPR).
    int rgw[9];
#pragma unroll
    for (int j = 0; j < 9; ++j)
        rgw[j] = reflect_idx(w0 - PAD + l + j);

    const float* xc = x + (size_t)wv * HW;   // this wave's channel plane
    const float* wp = wlds + l * KT;

    float a0 = 0.f, a1 = 0.f, a2 = 0.f;
#pragma unroll
    for (int i = 0; i < 9; ++i) {
        const float* row = xc + (size_t)reflect_idx(h - PAD + i) * W;

        float xv[9];
#pragma unroll
        for (int j = 0; j < 9; ++j)
            xv[j] = row[rgw[j]];           // normal loads: keep x in L2

        const float* wr = wp + i * 9;
        a0 = fmaf(xv[0], wr[0], a0);
        a1 = fmaf(xv[1], wr[1], a1);
        a2 = fmaf(xv[2], wr[2], a2);
        a0 = fmaf(xv[3], wr[3], a0);
        a1 = fmaf(xv[4], wr[4], a1);
        a2 = fmaf(xv[5], wr[5], a2);
        a0 = fmaf(xv[6], wr[6], a0);
        a1 = fmaf(xv[7], wr[7], a1);
        a2 = fmaf(xv[8], wr[8], a2);
    }

    __builtin_nontemporal_store(a0 + a1 + a2,
                                &out[(size_t)wv * HW + h * W + w0 + l]);
}

extern "C" void kernel_launch(void* const* d_in, const int* in_sizes, int n_in,
                              void* d_out, int out_size, void* d_ws, size_t ws_size,
                              hipStream_t stream) {
    const float* x  = (const float*)d_in[0];
    const float* kf = (const float*)d_in[1];
    float* out = (float*)d_out;

    dim3 block(192);
    dim3 grid(H * (W / SEGW));   // 4096 blocks x 3 waves
    svblur_kernel<<<grid, block, 0, stream>>>(x, kf, out);
}

// Round 11
// 23.851 us; speedup vs baseline: 1.2755x; 1.2755x over previous
//
#include <hip/hip_runtime.h>
#include <stdint.h>

#define H 512
#define W 512
#define HW (H * W)
#define KT 81       // 9x9 taps per pixel
#define PAD 4
#define SEGW 64     // pixels per segment
#define SEGDW (SEGW * KT)   // 5184 dwords of weights per segment
#define SPB 2       // segments per block (contiguous 41.5 KB kf stream)

typedef const __attribute__((address_space(1))) void* gptr1_t;
typedef __attribute__((address_space(3))) void* lptr3_t;

__device__ __forceinline__ int reflect_idx(int p) {
    // jnp.pad mode="reflect": pad (4) < 512, one fold suffices
    if (p < 0) p = -p;
    if (p >= H) p = 2 * H - 2 - p;
    return p;
}

// 256 threads = 4 waves: waves 0-2 compute channels 0-2 of a 64-px segment;
// wave 3 is a dedicated PRODUCER streaming the next segment's weights into
// the other half of an LDS ping-pong buffer via global_load_lds DMA.
// Race-freedom: __syncthreads() drains the issuing wave's vmcnt before
// s_barrier, so when all waves pass the barrier the prefetched buffer is
// complete, and compute waves finished reading the old buffer before it.
// Goal: keep the kf read stream continuously in flight (Little's law) instead
// of the stage-burst/compute-pause pattern of R1-R10.
// Weight readback: dword stride 81 -> bank (17*l+t) mod 32 is a permutation
// -> conflict-free, pairs into ds_read2_b32.
__global__ __launch_bounds__(256) void svblur_kernel(
    const float* __restrict__ x,
    const float* __restrict__ kf,
    float* __restrict__ out)
{
    __shared__ float wlds[2][SEGDW];   // 2 x 20736 B

    const int tid = (int)threadIdx.x;
    const int l   = tid & 63;           // lane
    const int wv  = tid >> 6;           // 0..2 = channel waves, 3 = producer
    const int seg0 = (int)blockIdx.x * SPB;

    const uint32_t* wsrc0 = (const uint32_t*)(kf + (size_t)seg0 * SEGDW);

    // ---- Producer: stage segment 0 into buf 0.
    if (wv == 3) {
        char* dst = (char*)&wlds[0][0];
#pragma unroll
        for (int k = 0; k < 20; ++k)
            __builtin_amdgcn_global_load_lds(
                (gptr1_t)(wsrc0 + k * 256 + l * 4),
                (lptr3_t)(dst + k * 1024), 16, 0, 0);
        if (l < 16)
            __builtin_amdgcn_global_load_lds(
                (gptr1_t)(wsrc0 + 20 * 256 + l * 4),
                (lptr3_t)(dst + 20 * 1024), 16, 0, 0);
    }
    __syncthreads();   // buf0 complete

    const float* xc = x + (size_t)wv * HW;   // channel plane (wv<3 only)

    for (int s = 0; s < SPB; ++s) {
        if (wv == 3) {
            // ---- Producer: stream segment s+1 into the other buffer NOW;
            // it lands while the compute waves work on segment s.
            if (s + 1 < SPB) {
                const uint32_t* wsn = wsrc0 + (size_t)(s + 1) * SEGDW;
                char* dst = (char*)&wlds[(s + 1) & 1][0];
#pragma unroll
                for (int k = 0; k < 20; ++k)
                    __builtin_amdgcn_global_load_lds(
                        (gptr1_t)(wsn + k * 256 + l * 4),
                        (lptr3_t)(dst + k * 1024), 16, 0, 0);
                if (l < 16)
                    __builtin_amdgcn_global_load_lds(
                        (gptr1_t)(wsn + 20 * 256 + l * 4),
                        (lptr3_t)(dst + 20 * 1024), 16, 0, 0);
            }
        } else {
            // ---- Compute segment seg0+s, channel wv (R4's proven body).
            const int seg = seg0 + s;
            const int h   = seg >> 3;
            const int w0  = (seg & 7) << 6;

            int rgw[9];
#pragma unroll
            for (int j = 0; j < 9; ++j)
                rgw[j] = reflect_idx(w0 - PAD + l + j);

            const float* wp = &wlds[s & 1][l * KT];
            float a0 = 0.f, a1 = 0.f, a2 = 0.f;
#pragma unroll
            for (int i = 0; i < 9; ++i) {
                const float* row = xc + (size_t)reflect_idx(h - PAD + i) * W;
                float xv[9];
#pragma unroll
                for (int j = 0; j < 9; ++j)
                    xv[j] = row[rgw[j]];       // coalesced, L2-resident band
                const float* wr = wp + i * 9;
                a0 = fmaf(xv[0], wr[0], a0);
                a1 = fmaf(xv[1], wr[1], a1);
                a2 = fmaf(xv[2], wr[2], a2);
                a0 = fmaf(xv[3], wr[3], a0);
                a1 = fmaf(xv[4], wr[4], a1);
                a2 = fmaf(xv[5], wr[5], a2);
                a0 = fmaf(xv[6], wr[6], a0);
                a1 = fmaf(xv[7], wr[7], a1);
                a2 = fmaf(xv[8], wr[8], a2);
            }
            out[(size_t)wv * HW + h * W + w0 + l] = a0 + a1 + a2;
        }
        __syncthreads();   // compute done with buf[s&1]; producer's DMA for
                           // s+1 drained (vmcnt(0) precedes its s_barrier)
    }
}

extern "C" void kernel_launch(void* const* d_in, const int* in_sizes, int n_in,
                              void* d_out, int out_size, void* d_ws, size_t ws_size,
                              hipStream_t stream) {
    const float* x  = (const float*)d_in[0];
    const float* kf = (const float*)d_in[1];
    float* out = (float*)d_out;

    dim3 block(256);
    dim3 grid((H * (W / SEGW)) / SPB);   // 2048 blocks x 2 segments
    svblur_kernel<<<grid, block, 0, stream>>>(x, kf, out);
}